// Round 3
// 621.852 us; speedup vs baseline: 1.0064x; 1.0064x over previous
//
#include <hip/hip_runtime.h>
#include <hip/hip_bf16.h>

#define TLEN 4096
#define EDIM 2048
#define DDIM 128
#define BSZ  8
#define NT   32            // TLEN/128
#define MROWS (BSZ*TLEN)   // 32768
#define NSLOT 528          // NT*(NT+1)/2 lower-tri tiles per batch

typedef unsigned short u16;
typedef __attribute__((ext_vector_type(8))) short bf16x8;  // 8 bf16 in 4 VGPRs
typedef __attribute__((ext_vector_type(4))) float f32x4;

// exp(scale * s) = exp2(C1 * s), scale = 1/sqrt(128)
#define C1F (0.08838834764831845f * 1.4426950408889634f)

__device__ __forceinline__ u16 f2bf(float f) {
  unsigned u = __builtin_bit_cast(unsigned, f);
  u += 0x7FFFu + ((u >> 16) & 1u);   // RNE
  return (u16)(u >> 16);
}
__device__ __forceinline__ float bf2f(u16 h) {
  unsigned u = ((unsigned)h) << 16;
  return __builtin_bit_cast(float, u);
}

// async global->LDS, 16B per lane; LDS dest = wave-uniform base + lane*16
__device__ __forceinline__ void async_ld16(const void* g, void* lds) {
  __builtin_amdgcn_global_load_lds(
      (const __attribute__((address_space(1))) unsigned int*)(g),
      (__attribute__((address_space(3))) unsigned int*)(lds), 16, 0, 0);
}

// XOR-swizzled byte offsets (conflict-free frag reads; verified: 0 conflicts)
__device__ __forceinline__ int swz16(int row, int chunk) {   // 256B rows
  return row * 256 + ((chunk ^ (row & 15)) << 4);
}
__device__ __forceinline__ int swz8(int row, int chunk) {    // 128B rows
  return row * 128 + ((chunk ^ (row & 7)) << 4);
}

// ---------------------------------------------------------------------------
__global__ __launch_bounds__(256) void zero_f32(float* __restrict__ out,
                                                float* __restrict__ denom) {
  size_t i = (size_t)blockIdx.x * 256 + threadIdx.x;
  float4 z = {0.f, 0.f, 0.f, 0.f};
  if (i < (size_t)MROWS * DDIM / 4) ((float4*)out)[i] = z;
  if (i < (size_t)BSZ * TLEN / 4) ((float4*)denom)[i] = z;
}

// ---------------------------------------------------------------------------
// Wt[w][n][k] = bf16(W_w[k][n])
__global__ __launch_bounds__(256) void prep_w(const float* __restrict__ Wq,
                                              const float* __restrict__ Wk,
                                              const float* __restrict__ Wv,
                                              u16* __restrict__ Wt) {
  int g = blockIdx.x * 256 + threadIdx.x;
  int w = g >> 15;
  int rem = g & 32767;
  int n = rem >> 8;
  int k0 = (rem & 255) * 8;
  const float* W = (w == 0) ? Wq : (w == 1) ? Wk : Wv;
  unsigned pk[4];
  for (int i = 0; i < 4; ++i) {
    u16 lo = f2bf(W[(size_t)(k0 + 2 * i) * DDIM + n]);
    u16 hi = f2bf(W[(size_t)(k0 + 2 * i + 1) * DDIM + n]);
    pk[i] = (unsigned)lo | ((unsigned)hi << 16);
  }
  uint4 v; v.x = pk[0]; v.y = pk[1]; v.z = pk[2]; v.w = pk[3];
  *(uint4*)(Wt + ((size_t)(w * DDIM + n) * EDIM + k0)) = v;
}

// ---------------------------------------------------------------------------
// qkv GEMM — R4: counted-vmcnt double-buffered pipeline at 64 KB static LDS
// (R1/R2's 128 KB static __shared__ is the suspected container-killer; every
// kernel that ever passed here used <=64 KB).  Split per weight: block =
// 128M x 128N for one of Wq/Wk/Wv; blockIdx.x = weight so the 3 blocks
// sharing an x-slice are dispatch-adjacent (L3 serves the re-reads).
// Steady state: B-DMA(kt+1) lands under MFMA(kt); A global loads for kt+2
// stay IN FLIGHT across the barrier (vmcnt(4), never 0 in the main loop).
__global__ __launch_bounds__(512, 4) void qkv_gemm(const float* __restrict__ x,
                                                   const u16* __restrict__ Wt,
                                                   u16* __restrict__ qkvb) {
  __shared__ u16 As[2][128 * 64];   // 2 x 16 KB
  __shared__ u16 Bs[2][128 * 64];   // 2 x 16 KB   (total 64 KB)
  const int tid = threadIdx.x, lane = tid & 63, wave = tid >> 6;
  const int quad = lane >> 4, l15 = lane & 15;
  const int w = blockIdx.x;              // weight: 0=q 1=k 2=v
  const int m0 = blockIdx.y * 128;
  const int wm = wave & 1, wn = wave >> 1;   // 2M x 4N wave grid
  const int NK = EDIM / 64;   // 32
  const u16* Wtw = Wt + (size_t)w * DDIM * EDIM;

  const f32x4 zero = {0.f, 0.f, 0.f, 0.f};
  f32x4 acc[4][2];
  for (int mi = 0; mi < 4; ++mi)
    for (int ni = 0; ni < 2; ++ni) acc[mi][ni] = zero;

  int arow[4], af4[4];
  for (int i = 0; i < 4; ++i) {
    int c = i * 512 + tid;
    arow[i] = c >> 4;
    af4[i] = c & 15;
  }
  float4 ap[4];

#define LOADA(KT)                                                            \
  for (int i = 0; i < 4; ++i)                                                \
    ap[i] = *(const float4*)(x + (size_t)(m0 + arow[i]) * EDIM + (KT)*64 +   \
                             af4[i] * 4);

#define ISSUEB(KT, BUF)                                                      \
  {                                                                          \
    const int k0_ = (KT)*64;                                                 \
    for (int e = 0; e < 2; ++e) {                                            \
      int rb = (wave * 2 + e) * 8;                                           \
      int r = rb + (lane >> 3);                                              \
      int c = (lane & 7) ^ (r & 7);                                          \
      async_ld16((const char*)(Wtw + (size_t)r * EDIM + k0_) + c * 16,       \
                 (char*)(BUF) + rb * 128);                                   \
    }                                                                        \
  }

#define CVTA(BUF)                                                            \
  for (int i = 0; i < 4; ++i) {                                              \
    uint2 pk;                                                                \
    pk.x = (unsigned)f2bf(ap[i].x) | ((unsigned)f2bf(ap[i].y) << 16);        \
    pk.y = (unsigned)f2bf(ap[i].z) | ((unsigned)f2bf(ap[i].w) << 16);        \
    *(uint2*)((char*)(BUF) + swz8(arow[i], af4[i] >> 1) + (af4[i] & 1) * 8) = pk; \
  }

  // ---- prologue: fill buffer 0, leave A(1) regs in flight across barrier
  LOADA(0)
  ISSUEB(0, Bs[0])
  asm volatile("s_waitcnt vmcnt(2)" ::: "memory");   // A(0) regs ready
  CVTA(As[0])
  LOADA(1)
  asm volatile("s_waitcnt vmcnt(4) lgkmcnt(0)" ::: "memory");  // B(0) landed
  __builtin_amdgcn_s_barrier();

  for (int kt = 0; kt < NK; ++kt) {
    const int cur = kt & 1, nxt = cur ^ 1;
    if (kt + 1 < NK) {
      ISSUEB(kt + 1, Bs[nxt])                        // DMA into alt buffer
      asm volatile("s_waitcnt vmcnt(2)" ::: "memory");  // A(kt+1) regs ready
      CVTA(As[nxt])
      if (kt + 2 < NK) { LOADA(kt + 2) }             // stays in flight
    }
    for (int ks = 0; ks < 2; ++ks) {
      const int ch = ks * 4 + quad;
      bf16x8 afr[4], bfr[2];
      for (int mi = 0; mi < 4; ++mi)
        afr[mi] = *(const bf16x8*)((char*)As[cur] + swz8(wm * 64 + mi * 16 + l15, ch));
      for (int ni = 0; ni < 2; ++ni)
        bfr[ni] = *(const bf16x8*)((char*)Bs[cur] + swz8(wn * 32 + ni * 16 + l15, ch));
      for (int mi = 0; mi < 4; ++mi)
        for (int ni = 0; ni < 2; ++ni)
          acc[mi][ni] = __builtin_amdgcn_mfma_f32_16x16x32_bf16(afr[mi], bfr[ni], acc[mi][ni], 0, 0, 0);
    }
    if (kt + 1 < NK) {
      if (kt + 2 < NK) {
        // B(kt+1) landed; A(kt+2) (4 newest) stays in flight
        asm volatile("s_waitcnt vmcnt(4) lgkmcnt(0)" ::: "memory");
      } else {
        asm volatile("s_waitcnt vmcnt(0) lgkmcnt(0)" ::: "memory");
      }
      __builtin_amdgcn_sched_barrier(0);
      __builtin_amdgcn_s_barrier();
    }
  }
#undef LOADA
#undef ISSUEB
#undef CVTA
  u16* ob = qkvb + (size_t)w * MROWS * DDIM;
  for (int mi = 0; mi < 4; ++mi)
    for (int ni = 0; ni < 2; ++ni) {
      int n = wn * 32 + ni * 16 + l15;
      for (int r = 0; r < 4; ++r) {
        int row = m0 + wm * 64 + mi * 16 + quad * 4 + r;
        ob[(size_t)row * DDIM + n] = f2bf(acc[mi][ni][r]);
      }
    }
}

// ---------------------------------------------------------------------------
// score_k: block (jt, ic, b) fixes key-tile jt, iterates a chunk of i-tiles.
// Writes E = exp(scale*s)*mask (bf16) into packed tri-tile storage, and
// atomically accumulates column sums into denom.  Steady loop is BARRIER-FREE:
// each wave's Q-stage rows == its A-frag rows == its E rows == its readback
// rows (wave-local LDS); only K (read-only after init) is shared.
__global__ __launch_bounds__(256) void score_k(const u16* __restrict__ qb,
                                               const u16* __restrict__ kb,
                                               char* __restrict__ Epack,
                                               float* __restrict__ denom) {
  __shared__ u16 Kbuf[128 * 128];
  __shared__ u16 Qbuf[128 * 128];
  const int tid = threadIdx.x, lane = tid & 63, wave = tid >> 6;
  const int quad = lane >> 4, l15 = lane & 15;
  const int jt = blockIdx.x, ic = blockIdx.y, b = blockIdx.z;
  const int len = NT - jt;
  const int cl = (len + 3) >> 2;
  if (ic * cl >= len) return;
  const int beg = jt + ic * cl;
  const int end = (beg + cl < NT) ? beg + cl : NT;
  const int j0 = jt * 128;

  {  // stage K tile once (swizzled rows, wave-split)
    const char* gk = (const char*)kb + (size_t)(b * TLEN + j0) * 256;
    for (int e = 0; e < 8; ++e) {
      int rb = (wave * 8 + e) * 4;
      int r = rb + (lane >> 4);
      int c = l15 ^ (r & 15);
      async_ld16(gk + r * 256 + c * 16, (char*)Kbuf + rb * 256);
    }
  }
  __builtin_amdgcn_s_waitcnt(0);
  __syncthreads();

  float csum[8];
  for (int ni = 0; ni < 8; ++ni) csum[ni] = 0.f;
  const f32x4 zero = {0.f, 0.f, 0.f, 0.f};

  for (int it = beg; it < end; ++it) {
    const int i0 = it * 128;
    {  // stage this wave's 32 Q rows (wave-local -> no barrier)
      const char* gq = (const char*)qb + (size_t)(b * TLEN + i0) * 256;
      for (int e = 0; e < 8; ++e) {
        int rb = (wave * 8 + e) * 4;
        int r = rb + (lane >> 4);
        int c = l15 ^ (r & 15);
        async_ld16(gq + r * 256 + c * 16, (char*)Qbuf + rb * 256);
      }
    }
    __builtin_amdgcn_s_waitcnt(0);   // own loads landed (wave-local)

    f32x4 accS[2][8];
    for (int mi = 0; mi < 2; ++mi)
      for (int ni = 0; ni < 8; ++ni) accS[mi][ni] = zero;
    for (int ks = 0; ks < 4; ++ks) {
      const int ch = ks * 4 + quad;
      bf16x8 afr[2], kfr[8];
      for (int mi = 0; mi < 2; ++mi)
        afr[mi] = *(const bf16x8*)((char*)Qbuf + swz16(wave * 32 + mi * 16 + l15, ch));
      for (int ni = 0; ni < 8; ++ni)
        kfr[ni] = *(const bf16x8*)((char*)Kbuf + swz16(ni * 16 + l15, ch));
      for (int mi = 0; mi < 2; ++mi)
        for (int ni = 0; ni < 8; ++ni)
          accS[mi][ni] = __builtin_amdgcn_mfma_f32_16x16x32_bf16(afr[mi], kfr[ni], accS[mi][ni], 0, 0, 0);
    }
    // epilogue: E = exp2(C1*s) (masked), column-sum, write E back into Qbuf
    const bool diag = (it == jt);
    for (int mi = 0; mi < 2; ++mi)
      for (int ni = 0; ni < 8; ++ni)
        for (int r = 0; r < 4; ++r) {
          float e = exp2f(C1F * accS[mi][ni][r]);
          int rrow = wave * 32 + mi * 16 + quad * 4 + r;
          int jl = ni * 16 + l15;
          if (diag && (i0 + rrow) < (j0 + jl)) e = 0.f;
          csum[ni] += e;
          *(u16*)((char*)Qbuf + swz16(rrow, jl >> 3) + (jl & 7) * 2) = f2bf(e);
        }
    // readback own 32 rows -> coalesced global store of the E tile
    char* eslot = Epack + (((size_t)b * NSLOT + (size_t)it * (it + 1) / 2 + jt) << 15);
    for (int e = 0; e < 8; ++e) {
      int row = wave * 32 + e * 4 + (lane >> 4);
      bf16x8 v = *(const bf16x8*)((char*)Qbuf + swz16(row, l15));
      *(bf16x8*)(eslot + row * 256 + l15 * 16) = v;
    }
  }
  // reduce csum: quad-lanes, then cross-wave via LDS, then atomics
  for (int ni = 0; ni < 8; ++ni) {
    csum[ni] += __shfl_xor(csum[ni], 16, 64);
    csum[ni] += __shfl_xor(csum[ni], 32, 64);
  }
  __syncthreads();
  float* red = (float*)Kbuf;
  if (lane < 16)
    for (int ni = 0; ni < 8; ++ni)
      red[wave * 128 + ni * 16 + lane] = csum[ni];
  __syncthreads();
  if (tid < 128)
    atomicAdd(&denom[(size_t)b * TLEN + j0 + tid],
              red[tid] + red[128 + tid] + red[256 + tid] + red[384 + tid]);
}

// ---------------------------------------------------------------------------
// vbT[b][d][t] = vb[b][t][d] / denom[b][t]   (V row-scale folds softmax denom)
__global__ __launch_bounds__(256) void vscale_t(const u16* __restrict__ vb,
                                                const float* __restrict__ denom,
                                                u16* __restrict__ vbT) {
  __shared__ u16 tile[128 * 136];
  const int tid = threadIdx.x;
  const int t0 = blockIdx.x * 128, b = blockIdx.y;
  for (int i = 0; i < 8; ++i) {
    int c = tid + i * 256;
    int tl = c >> 4, ch = c & 15;
    float rd = 1.0f / denom[(size_t)b * TLEN + t0 + tl];
    uint4 v = *(const uint4*)(vb + ((size_t)(b * TLEN + t0 + tl) * DDIM + ch * 8));
    unsigned w[4] = {v.x, v.y, v.z, v.w};
    unsigned o[4];
    for (int j = 0; j < 4; ++j) {
      float lo = bf2f((u16)w[j]) * rd;
      float hi = bf2f((u16)(w[j] >> 16)) * rd;
      o[j] = (unsigned)f2bf(lo) | ((unsigned)f2bf(hi) << 16);
    }
    uint4 ov; ov.x = o[0]; ov.y = o[1]; ov.z = o[2]; ov.w = o[3];
    *(uint4*)(tile + tl * 136 + ch * 8) = ov;
  }
  __syncthreads();
  for (int i = 0; i < 8; ++i) {
    int c = tid + i * 256;
    int d = c >> 4, ch = c & 15;
    unsigned pk[4];
    for (int j = 0; j < 4; ++j) {
      u16 lo = tile[(ch * 8 + 2 * j) * 136 + d];
      u16 hi = tile[(ch * 8 + 2 * j + 1) * 136 + d];
      pk[j] = (unsigned)lo | ((unsigned)hi << 16);
    }
    uint4 v; v.x = pk[0]; v.y = pk[1]; v.z = pk[2]; v.w = pk[3];
    *(uint4*)(vbT + ((size_t)(b * DDIM + d) * TLEN + t0 + ch * 8)) = v;
  }
}

// ---------------------------------------------------------------------------
// pv_k: out[b,i,:] (+)= E[i,:] @ V'  — pure m97-style GEMM, BK=64,
// K-loop over 64-wide j sub-steps chunked by jc (16 sub-steps/chunk).
__global__ __launch_bounds__(256, 3) void pv_k(const char* __restrict__ Epack,
                                               const u16* __restrict__ vbT,
                                               float* __restrict__ out) {
  __shared__ u16 Es[128 * 64];   // [i][j64] swizzled 128B rows
  __shared__ u16 Vs[128 * 64];   // [d][j64] swizzled 128B rows
  const int tid = threadIdx.x, lane = tid & 63, wave = tid >> 6;
  const int quad = lane >> 4, l15 = lane & 15;
  const int it = blockIdx.x, jc = blockIdx.y, b = blockIdx.z;
  const int nsub = 2 * (it + 1);
  const int sBeg = jc * 16;
  if (sBeg >= nsub) return;
  const int sEnd = (sBeg + 16 < nsub) ? sBeg + 16 : nsub;
  const int i0 = it * 128;
  const int wm = wave & 1, wn = wave >> 1;

  const f32x4 zero = {0.f, 0.f, 0.f, 0.f};
  f32x4 accO[4][4];
  for (int mi = 0; mi < 4; ++mi)
    for (int ni = 0; ni < 4; ++ni) accO[mi][ni] = zero;

  const size_t triBase = ((size_t)b * NSLOT + (size_t)it * (it + 1) / 2) << 15;
  const char* vbase = (const char*)vbT + (size_t)b * DDIM * TLEN * 2;

  for (int s = sBeg; s < sEnd; ++s) {
    const int jt = s >> 1, h = s & 1;
    __syncthreads();
    {
      const char* eb = Epack + triBase + ((size_t)jt << 15) + h * 128;
      const char* vb2 = vbase + s * 128;
      for (int e = 0; e < 4; ++e) {
        int rb = (wave * 4 + e) * 8;
        int r = rb + (lane >> 3);
        int c = (lane & 7) ^ (r & 7);
        async_ld16(eb + r * 256 + c * 16, (char*)Es + rb * 128);
        async_ld16(vb2 + (size_t)r * (TLEN * 2) + c * 16, (char*)Vs + rb * 128);
      }
    }
    __builtin_amdgcn_s_waitcnt(0);
    __syncthreads();
    for (int ks = 0; ks < 2; ++ks) {
      const int ch = ks * 4 + quad;
      bf16x8 afr[4], bfr[4];
      for (int mi = 0; mi < 4; ++mi)
        afr[mi] = *(const bf16x8*)((char*)Es + swz8(wm * 64 + mi * 16 + l15, ch));
      for (int ni = 0; ni < 4; ++ni)
        bfr[ni] = *(const bf16x8*)((char*)Vs + swz8(wn * 64 + ni * 16 + l15, ch));
      for (int mi = 0; mi < 4; ++mi)
        for (int ni = 0; ni < 4; ++ni)
          accO[mi][ni] = __builtin_amdgcn_mfma_f32_16x16x32_bf16(afr[mi], bfr[ni], accO[mi][ni], 0, 0, 0);
    }
  }
  const bool excl = (it < 8);   // single contributing block -> plain store
  for (int mi = 0; mi < 4; ++mi)
    for (int ni = 0; ni < 4; ++ni) {
      int d = wn * 64 + ni * 16 + l15;
      for (int r = 0; r < 4; ++r) {
        int row = i0 + wm * 64 + mi * 16 + quad * 4 + r;
        float* dst = &out[((size_t)b * TLEN + row) * DDIM + d];
        if (excl) *dst = accO[mi][ni][r];
        else atomicAdd(dst, accO[mi][ni][r]);
      }
    }
}

// ---------------------------------------------------------------------------
extern "C" void kernel_launch(void* const* d_in, const int* in_sizes, int n_in,
                              void* d_out, int out_size, void* d_ws, size_t ws_size,
                              hipStream_t stream) {
  const float* x  = (const float*)d_in[0];
  const float* Wq = (const float*)d_in[1];
  const float* Wk = (const float*)d_in[2];
  const float* Wv = (const float*)d_in[3];
  float* out = (float*)d_out;

  u16* qb  = (u16*)d_ws;                       // [32768][128] bf16
  u16* kb  = qb  + (size_t)MROWS * DDIM;
  u16* vb  = kb  + (size_t)MROWS * DDIM;
  u16* vbT = vb  + (size_t)MROWS * DDIM;       // [8][128][4096]
  u16* Wt  = vbT + (size_t)MROWS * DDIM;       // [3][128][2048]
  float* denom = (float*)(Wt + (size_t)3 * DDIM * EDIM);  // [8][4096] fp32
  char* Epack = (char*)(denom + (size_t)BSZ * TLEN);      // 8*528*32KB = 138 MB

  hipLaunchKernelGGL(zero_f32, dim3(4096), dim3(256), 0, stream, out, denom);
  hipLaunchKernelGGL(prep_w, dim3(384), dim3(256), 0, stream, Wq, Wk, Wv, Wt);
  hipLaunchKernelGGL(qkv_gemm, dim3(3, 256), dim3(512), 0, stream, x, Wt, qb);
  hipLaunchKernelGGL(score_k, dim3(NT, 4, BSZ), dim3(256), 0, stream, qb, kb, Epack, denom);
  hipLaunchKernelGGL(vscale_t, dim3(NT, BSZ), dim3(256), 0, stream, vb, denom, vbT);
  hipLaunchKernelGGL(pv_k, dim3(NT, 4, BSZ), dim3(256), 0, stream, Epack, vbT, out);
}

// Round 4
// 605.400 us; speedup vs baseline: 1.0337x; 1.0272x over previous
//
#include <hip/hip_runtime.h>
#include <hip/hip_bf16.h>

#define TLEN 4096
#define EDIM 2048
#define DDIM 128
#define BSZ  8
#define NT   32            // TLEN/128
#define MROWS (BSZ*TLEN)   // 32768
#define NSLOT 528          // NT*(NT+1)/2 lower-tri tiles per batch

typedef unsigned short u16;
typedef __attribute__((ext_vector_type(8))) short bf16x8;  // 8 bf16 in 4 VGPRs
typedef __attribute__((ext_vector_type(4))) float f32x4;

// exp(scale * s) = exp2(C1 * s), scale = 1/sqrt(128)
#define C1F (0.08838834764831845f * 1.4426950408889634f)

__device__ __forceinline__ u16 f2bf(float f) {
  unsigned u = __builtin_bit_cast(unsigned, f);
  u += 0x7FFFu + ((u >> 16) & 1u);   // RNE
  return (u16)(u >> 16);
}
__device__ __forceinline__ float bf2f(u16 h) {
  unsigned u = ((unsigned)h) << 16;
  return __builtin_bit_cast(float, u);
}

// async global->LDS, 16B per lane; LDS dest = wave-uniform base + lane*16
__device__ __forceinline__ void async_ld16(const void* g, void* lds) {
  __builtin_amdgcn_global_load_lds(
      (const __attribute__((address_space(1))) unsigned int*)(g),
      (__attribute__((address_space(3))) unsigned int*)(lds), 16, 0, 0);
}

// XOR-swizzled byte offsets (conflict-free frag reads)
__device__ __forceinline__ int swz16(int row, int chunk) {   // 256B rows
  return row * 256 + ((chunk ^ (row & 15)) << 4);
}
__device__ __forceinline__ int swz8(int row, int chunk) {    // 128B rows
  return row * 128 + ((chunk ^ (row & 7)) << 4);
}
// 64B rows (BK=32 bf16): slot-in-128B-line = (row&1)*4 | (chunk ^ rowpair).
// A 64-lane b128 frag read (16 rows x 4 quads) hits 64 distinct 16B slots.
__device__ __forceinline__ int swz4(int row, int chunk) {
  return (row >> 1) * 128 + ((((row & 1) << 2) | ((chunk ^ (row >> 1)) & 3)) << 4);
}

// ---------------------------------------------------------------------------
__global__ __launch_bounds__(256) void zero_f32(float* __restrict__ out,
                                                float* __restrict__ denom) {
  size_t i = (size_t)blockIdx.x * 256 + threadIdx.x;
  float4 z = {0.f, 0.f, 0.f, 0.f};
  if (i < (size_t)MROWS * DDIM / 4) ((float4*)out)[i] = z;
  if (i < (size_t)BSZ * TLEN / 4) ((float4*)denom)[i] = z;
}

// ---------------------------------------------------------------------------
// Wt[w][n][k] = bf16(W_w[k][n])
__global__ __launch_bounds__(256) void prep_w(const float* __restrict__ Wq,
                                              const float* __restrict__ Wk,
                                              const float* __restrict__ Wv,
                                              u16* __restrict__ Wt) {
  int g = blockIdx.x * 256 + threadIdx.x;
  int w = g >> 15;
  int rem = g & 32767;
  int n = rem >> 8;
  int k0 = (rem & 255) * 8;
  const float* W = (w == 0) ? Wq : (w == 1) ? Wk : Wv;
  unsigned pk[4];
  for (int i = 0; i < 4; ++i) {
    u16 lo = f2bf(W[(size_t)(k0 + 2 * i) * DDIM + n]);
    u16 hi = f2bf(W[(size_t)(k0 + 2 * i + 1) * DDIM + n]);
    pk[i] = (unsigned)lo | ((unsigned)hi << 16);
  }
  uint4 v; v.x = pk[0]; v.y = pk[1]; v.z = pk[2]; v.w = pk[3];
  *(uint4*)(Wt + ((size_t)(w * DDIM + n) * EDIM + k0)) = v;
}

// ---------------------------------------------------------------------------
// Fused q,k,v GEMM — R5: single x read (268 MB, 42 µs HBM floor) with the
// R3-hardware-validated counted-vmcnt double-buffer pipeline, at 64 KB static
// LDS (128 KB static __shared__ kills the container — R1/R2).  BK=32:
// As 2x8KB + Bs 2x24KB.  Steady state per kt: 3 B-DMAs for kt+1 land under
// MFMA(kt); 2 A global loads for kt+2 stay IN FLIGHT across the barrier
// (vmcnt never 0 in the main loop).  vmcnt counts rely on in-order retirement:
// top vmcnt(3) retires the 2 A-loads, bottom vmcnt(2) retires the 3 B-DMAs.
__global__ __launch_bounds__(512, 2) void qkv_gemm(const float* __restrict__ x,
                                                   const u16* __restrict__ Wt,
                                                   u16* __restrict__ qkvb) {
  __shared__ u16 As[2][128 * 32];   // 2 x 8 KB
  __shared__ u16 Bs[2][384 * 32];   // 2 x 24 KB   (total 64 KB)
  const int tid = threadIdx.x, lane = tid & 63, wave = tid >> 6;
  const int quad = lane >> 4, l15 = lane & 15;
  const int m0 = blockIdx.x * 128;
  const int wm = wave & 1, wn = wave >> 1;   // 2M x 4N wave grid
  const int NK = EDIM / 32;   // 64

  const f32x4 zero = {0.f, 0.f, 0.f, 0.f};
  f32x4 acc[4][6];
  for (int mi = 0; mi < 4; ++mi)
    for (int ni = 0; ni < 6; ++ni) acc[mi][ni] = zero;

  // A tile per step: 128 rows x 32 fp32 = 1024 float4; 512 thr -> 2 each.
  int arow[2], af4[2];
  for (int i = 0; i < 2; ++i) {
    int c = i * 512 + tid;
    arow[i] = c >> 3;        // 8 float4 per row
    af4[i] = c & 7;
  }
  float4 ap[2];

  // B-DMA source pre-permutation: linear LDS slot g16 -> (row, chunk) of the
  // swz4 layout.  p = g16>>3 (128B line = row pair), s = g16&7:
  // row = 2p + (s>>2), chunk = (s&3) ^ (p&3).
  int brow[3], bch[3];
  for (int e = 0; e < 3; ++e) {
    int rb = (wave * 3 + e) * 16;          // 16 rows per DMA instruction
    int g16 = rb * 4 + lane;
    int p = g16 >> 3, s = g16 & 7;
    brow[e] = 2 * p + (s >> 2);
    bch[e] = (s & 3) ^ (p & 3);
  }

#define LOADA(KT)                                                            \
  for (int i = 0; i < 2; ++i)                                                \
    ap[i] = *(const float4*)(x + (size_t)(m0 + arow[i]) * EDIM + (KT)*32 +   \
                             af4[i] * 4);

#define ISSUEB(KT, BUF)                                                      \
  for (int e = 0; e < 3; ++e) {                                              \
    int rb = (wave * 3 + e) * 16;                                            \
    async_ld16((const char*)Wt + (size_t)brow[e] * (EDIM * 2) + (KT)*64 +    \
                   bch[e] * 16,                                              \
               (char*)(BUF) + rb * 64);                                      \
  }

#define CVTA(BUF)                                                            \
  for (int i = 0; i < 2; ++i) {                                              \
    uint2 pk;                                                                \
    pk.x = (unsigned)f2bf(ap[i].x) | ((unsigned)f2bf(ap[i].y) << 16);        \
    pk.y = (unsigned)f2bf(ap[i].z) | ((unsigned)f2bf(ap[i].w) << 16);        \
    *(uint2*)((char*)(BUF) + swz4(arow[i], af4[i] >> 1) + (af4[i] & 1) * 8) = pk; \
  }

  // ---- prologue: fill buffer 0, leave A(1) regs in flight across barrier
  LOADA(0)
  ISSUEB(0, Bs[0])
  asm volatile("s_waitcnt vmcnt(3)" ::: "memory");   // A(0) regs ready
  CVTA(As[0])
  LOADA(1)
  asm volatile("s_waitcnt vmcnt(2) lgkmcnt(0)" ::: "memory");  // B(0) landed
  __builtin_amdgcn_s_barrier();

  for (int kt = 0; kt < NK; ++kt) {
    const int cur = kt & 1, nxt = cur ^ 1;
    if (kt + 1 < NK) {
      ISSUEB(kt + 1, Bs[nxt])                        // DMA into alt buffer
      asm volatile("s_waitcnt vmcnt(3)" ::: "memory");  // A(kt+1) regs ready
      CVTA(As[nxt])
      if (kt + 2 < NK) { LOADA(kt + 2) }             // stays in flight
    }
    {
      bf16x8 afr[4], bfr[6];
      for (int mi = 0; mi < 4; ++mi)
        afr[mi] = *(const bf16x8*)((char*)As[cur] + swz4(wm * 64 + mi * 16 + l15, quad));
      for (int ni = 0; ni < 6; ++ni)
        bfr[ni] = *(const bf16x8*)((char*)Bs[cur] + swz4(wn * 96 + ni * 16 + l15, quad));
      for (int mi = 0; mi < 4; ++mi)
        for (int ni = 0; ni < 6; ++ni)
          acc[mi][ni] = __builtin_amdgcn_mfma_f32_16x16x32_bf16(afr[mi], bfr[ni], acc[mi][ni], 0, 0, 0);
    }
    if (kt + 1 < NK) {
      if (kt + 2 < NK) {
        // B(kt+1) landed; A(kt+2) (2 newest) stays in flight
        asm volatile("s_waitcnt vmcnt(2) lgkmcnt(0)" ::: "memory");
      } else {
        asm volatile("s_waitcnt vmcnt(0) lgkmcnt(0)" ::: "memory");
      }
      __builtin_amdgcn_sched_barrier(0);
      __builtin_amdgcn_s_barrier();
    }
  }
#undef LOADA
#undef ISSUEB
#undef CVTA
  for (int mi = 0; mi < 4; ++mi)
    for (int ni = 0; ni < 6; ++ni) {
      int n = wn * 96 + ni * 16 + l15;
      u16* ob = qkvb + (size_t)(n >> 7) * MROWS * DDIM;
      int nc = n & 127;
      for (int r = 0; r < 4; ++r) {
        int row = m0 + wm * 64 + mi * 16 + quad * 4 + r;
        ob[(size_t)row * DDIM + nc] = f2bf(acc[mi][ni][r]);
      }
    }
}

// ---------------------------------------------------------------------------
// score_k: block (jt, ic, b) fixes key-tile jt, iterates a chunk of i-tiles.
// Writes E = exp(scale*s)*mask (bf16) into packed tri-tile storage, and
// atomically accumulates column sums into denom.  Steady loop is BARRIER-FREE:
// each wave's Q-stage rows == its A-frag rows == its E rows == its readback
// rows (wave-local LDS); only K (read-only after init) is shared.
__global__ __launch_bounds__(256) void score_k(const u16* __restrict__ qb,
                                               const u16* __restrict__ kb,
                                               char* __restrict__ Epack,
                                               float* __restrict__ denom) {
  __shared__ u16 Kbuf[128 * 128];
  __shared__ u16 Qbuf[128 * 128];
  const int tid = threadIdx.x, lane = tid & 63, wave = tid >> 6;
  const int quad = lane >> 4, l15 = lane & 15;
  const int jt = blockIdx.x, ic = blockIdx.y, b = blockIdx.z;
  const int len = NT - jt;
  const int cl = (len + 3) >> 2;
  if (ic * cl >= len) return;
  const int beg = jt + ic * cl;
  const int end = (beg + cl < NT) ? beg + cl : NT;
  const int j0 = jt * 128;

  {  // stage K tile once (swizzled rows, wave-split)
    const char* gk = (const char*)kb + (size_t)(b * TLEN + j0) * 256;
    for (int e = 0; e < 8; ++e) {
      int rb = (wave * 8 + e) * 4;
      int r = rb + (lane >> 4);
      int c = l15 ^ (r & 15);
      async_ld16(gk + r * 256 + c * 16, (char*)Kbuf + rb * 256);
    }
  }
  __builtin_amdgcn_s_waitcnt(0);
  __syncthreads();

  float csum[8];
  for (int ni = 0; ni < 8; ++ni) csum[ni] = 0.f;
  const f32x4 zero = {0.f, 0.f, 0.f, 0.f};

  for (int it = beg; it < end; ++it) {
    const int i0 = it * 128;
    {  // stage this wave's 32 Q rows (wave-local -> no barrier)
      const char* gq = (const char*)qb + (size_t)(b * TLEN + i0) * 256;
      for (int e = 0; e < 8; ++e) {
        int rb = (wave * 8 + e) * 4;
        int r = rb + (lane >> 4);
        int c = l15 ^ (r & 15);
        async_ld16(gq + r * 256 + c * 16, (char*)Qbuf + rb * 256);
      }
    }
    __builtin_amdgcn_s_waitcnt(0);   // own loads landed (wave-local)

    f32x4 accS[2][8];
    for (int mi = 0; mi < 2; ++mi)
      for (int ni = 0; ni < 8; ++ni) accS[mi][ni] = zero;
    for (int ks = 0; ks < 4; ++ks) {
      const int ch = ks * 4 + quad;
      bf16x8 afr[2], kfr[8];
      for (int mi = 0; mi < 2; ++mi)
        afr[mi] = *(const bf16x8*)((char*)Qbuf + swz16(wave * 32 + mi * 16 + l15, ch));
      for (int ni = 0; ni < 8; ++ni)
        kfr[ni] = *(const bf16x8*)((char*)Kbuf + swz16(ni * 16 + l15, ch));
      for (int mi = 0; mi < 2; ++mi)
        for (int ni = 0; ni < 8; ++ni)
          accS[mi][ni] = __builtin_amdgcn_mfma_f32_16x16x32_bf16(afr[mi], kfr[ni], accS[mi][ni], 0, 0, 0);
    }
    // epilogue: E = exp2(C1*s) (masked), column-sum, write E back into Qbuf
    const bool diag = (it == jt);
    for (int mi = 0; mi < 2; ++mi)
      for (int ni = 0; ni < 8; ++ni)
        for (int r = 0; r < 4; ++r) {
          float e = exp2f(C1F * accS[mi][ni][r]);
          int rrow = wave * 32 + mi * 16 + quad * 4 + r;
          int jl = ni * 16 + l15;
          if (diag && (i0 + rrow) < (j0 + jl)) e = 0.f;
          csum[ni] += e;
          *(u16*)((char*)Qbuf + swz16(rrow, jl >> 3) + (jl & 7) * 2) = f2bf(e);
        }
    // readback own 32 rows -> coalesced global store of the E tile
    char* eslot = Epack + (((size_t)b * NSLOT + (size_t)it * (it + 1) / 2 + jt) << 15);
    for (int e = 0; e < 8; ++e) {
      int row = wave * 32 + e * 4 + (lane >> 4);
      bf16x8 v = *(const bf16x8*)((char*)Qbuf + swz16(row, l15));
      *(bf16x8*)(eslot + row * 256 + l15 * 16) = v;
    }
  }
  // reduce csum: quad-lanes, then cross-wave via LDS, then atomics
  for (int ni = 0; ni < 8; ++ni) {
    csum[ni] += __shfl_xor(csum[ni], 16, 64);
    csum[ni] += __shfl_xor(csum[ni], 32, 64);
  }
  __syncthreads();
  float* red = (float*)Kbuf;
  if (lane < 16)
    for (int ni = 0; ni < 8; ++ni)
      red[wave * 128 + ni * 16 + lane] = csum[ni];
  __syncthreads();
  if (tid < 128)
    atomicAdd(&denom[(size_t)b * TLEN + j0 + tid],
              red[tid] + red[128 + tid] + red[256 + tid] + red[384 + tid]);
}

// ---------------------------------------------------------------------------
// vbT[b][d][t] = vb[b][t][d] / denom[b][t]   (V row-scale folds softmax denom)
__global__ __launch_bounds__(256) void vscale_t(const u16* __restrict__ vb,
                                                const float* __restrict__ denom,
                                                u16* __restrict__ vbT) {
  __shared__ u16 tile[128 * 136];
  const int tid = threadIdx.x;
  const int t0 = blockIdx.x * 128, b = blockIdx.y;
  for (int i = 0; i < 8; ++i) {
    int c = tid + i * 256;
    int tl = c >> 4, ch = c & 15;
    float rd = 1.0f / denom[(size_t)b * TLEN + t0 + tl];
    uint4 v = *(const uint4*)(vb + ((size_t)(b * TLEN + t0 + tl) * DDIM + ch * 8));
    unsigned w[4] = {v.x, v.y, v.z, v.w};
    unsigned o[4];
    for (int j = 0; j < 4; ++j) {
      float lo = bf2f((u16)w[j]) * rd;
      float hi = bf2f((u16)(w[j] >> 16)) * rd;
      o[j] = (unsigned)f2bf(lo) | ((unsigned)f2bf(hi) << 16);
    }
    uint4 ov; ov.x = o[0]; ov.y = o[1]; ov.z = o[2]; ov.w = o[3];
    *(uint4*)(tile + tl * 136 + ch * 8) = ov;
  }
  __syncthreads();
  for (int i = 0; i < 8; ++i) {
    int c = tid + i * 256;
    int d = c >> 4, ch = c & 15;
    unsigned pk[4];
    for (int j = 0; j < 4; ++j) {
      u16 lo = tile[(ch * 8 + 2 * j) * 136 + d];
      u16 hi = tile[(ch * 8 + 2 * j + 1) * 136 + d];
      pk[j] = (unsigned)lo | ((unsigned)hi << 16);
    }
    uint4 v; v.x = pk[0]; v.y = pk[1]; v.z = pk[2]; v.w = pk[3];
    *(uint4*)(vbT + ((size_t)(b * DDIM + d) * TLEN + t0 + ch * 8)) = v;
  }
}

// ---------------------------------------------------------------------------
// pv_k: out[b,i,:] (+)= E[i,:] @ V'  — pure m97-style GEMM, BK=64,
// K-loop over 64-wide j sub-steps chunked by jc (16 sub-steps/chunk).
__global__ __launch_bounds__(256, 3) void pv_k(const char* __restrict__ Epack,
                                               const u16* __restrict__ vbT,
                                               float* __restrict__ out) {
  __shared__ u16 Es[128 * 64];   // [i][j64] swizzled 128B rows
  __shared__ u16 Vs[128 * 64];   // [d][j64] swizzled 128B rows
  const int tid = threadIdx.x, lane = tid & 63, wave = tid >> 6;
  const int quad = lane >> 4, l15 = lane & 15;
  const int it = blockIdx.x, jc = blockIdx.y, b = blockIdx.z;
  const int nsub = 2 * (it + 1);
  const int sBeg = jc * 16;
  if (sBeg >= nsub) return;
  const int sEnd = (sBeg + 16 < nsub) ? sBeg + 16 : nsub;
  const int i0 = it * 128;
  const int wm = wave & 1, wn = wave >> 1;

  const f32x4 zero = {0.f, 0.f, 0.f, 0.f};
  f32x4 accO[4][4];
  for (int mi = 0; mi < 4; ++mi)
    for (int ni = 0; ni < 4; ++ni) accO[mi][ni] = zero;

  const size_t triBase = ((size_t)b * NSLOT + (size_t)it * (it + 1) / 2) << 15;
  const char* vbase = (const char*)vbT + (size_t)b * DDIM * TLEN * 2;

  for (int s = sBeg; s < sEnd; ++s) {
    const int jt = s >> 1, h = s & 1;
    __syncthreads();
    {
      const char* eb = Epack + triBase + ((size_t)jt << 15) + h * 128;
      const char* vb2 = vbase + s * 128;
      for (int e = 0; e < 4; ++e) {
        int rb = (wave * 4 + e) * 8;
        int r = rb + (lane >> 3);
        int c = (lane & 7) ^ (r & 7);
        async_ld16(eb + r * 256 + c * 16, (char*)Es + rb * 128);
        async_ld16(vb2 + (size_t)r * (TLEN * 2) + c * 16, (char*)Vs + rb * 128);
      }
    }
    __builtin_amdgcn_s_waitcnt(0);
    __syncthreads();
    for (int ks = 0; ks < 2; ++ks) {
      const int ch = ks * 4 + quad;
      bf16x8 afr[4], bfr[4];
      for (int mi = 0; mi < 4; ++mi)
        afr[mi] = *(const bf16x8*)((char*)Es + swz8(wm * 64 + mi * 16 + l15, ch));
      for (int ni = 0; ni < 4; ++ni)
        bfr[ni] = *(const bf16x8*)((char*)Vs + swz8(wn * 64 + ni * 16 + l15, ch));
      for (int mi = 0; mi < 4; ++mi)
        for (int ni = 0; ni < 4; ++ni)
          accO[mi][ni] = __builtin_amdgcn_mfma_f32_16x16x32_bf16(afr[mi], bfr[ni], accO[mi][ni], 0, 0, 0);
    }
  }
  const bool excl = (it < 8);   // single contributing block -> plain store
  for (int mi = 0; mi < 4; ++mi)
    for (int ni = 0; ni < 4; ++ni) {
      int d = wn * 64 + ni * 16 + l15;
      for (int r = 0; r < 4; ++r) {
        int row = i0 + wm * 64 + mi * 16 + quad * 4 + r;
        float* dst = &out[((size_t)b * TLEN + row) * DDIM + d];
        if (excl) *dst = accO[mi][ni][r];
        else atomicAdd(dst, accO[mi][ni][r]);
      }
    }
}

// ---------------------------------------------------------------------------
extern "C" void kernel_launch(void* const* d_in, const int* in_sizes, int n_in,
                              void* d_out, int out_size, void* d_ws, size_t ws_size,
                              hipStream_t stream) {
  const float* x  = (const float*)d_in[0];
  const float* Wq = (const float*)d_in[1];
  const float* Wk = (const float*)d_in[2];
  const float* Wv = (const float*)d_in[3];
  float* out = (float*)d_out;

  u16* qb  = (u16*)d_ws;                       // [32768][128] bf16
  u16* kb  = qb  + (size_t)MROWS * DDIM;
  u16* vb  = kb  + (size_t)MROWS * DDIM;
  u16* vbT = vb  + (size_t)MROWS * DDIM;       // [8][128][4096]
  u16* Wt  = vbT + (size_t)MROWS * DDIM;       // [3][128][2048]
  float* denom = (float*)(Wt + (size_t)3 * DDIM * EDIM);  // [8][4096] fp32
  char* Epack = (char*)(denom + (size_t)BSZ * TLEN);      // 8*528*32KB = 138 MB

  hipLaunchKernelGGL(zero_f32, dim3(4096), dim3(256), 0, stream, out, denom);
  hipLaunchKernelGGL(prep_w, dim3(384), dim3(256), 0, stream, Wq, Wk, Wv, Wt);
  hipLaunchKernelGGL(qkv_gemm, dim3(256), dim3(512), 0, stream, x, Wt, qb);
  hipLaunchKernelGGL(score_k, dim3(NT, 4, BSZ), dim3(256), 0, stream, qb, kb, Epack, denom);
  hipLaunchKernelGGL(vscale_t, dim3(NT, BSZ), dim3(256), 0, stream, vb, denom, vbT);
  hipLaunchKernelGGL(pv_k, dim3(NT, 4, BSZ), dim3(256), 0, stream, Epack, vbT, out);
}